// Round 12
// baseline (181.247 us; speedup 1.0000x reference)
//
#include <hip/hip_runtime.h>
#include <hip/hip_bf16.h>

typedef __attribute__((ext_vector_type(8))) short short8;
typedef __attribute__((ext_vector_type(4))) short short4v;
typedef __attribute__((ext_vector_type(4))) float f32x4;

#define S_LEN 2048
#define DM 768
#define NH 12
#define HD 64
#define NB 2
#define MROWS (NB*S_LEN)          // 4096
#define NEGINF (-1.0e9f)
#define XEL 3145728               // 4096*768 elements
#define WEL 589824                // 768*768

__device__ __forceinline__ unsigned short f2bf(float x) {
    __hip_bfloat16 h = __float2bfloat16(x);   // RNE; compiler pairs into v_cvt_pk_bf16_f32
    return *reinterpret_cast<unsigned short*>(&h);
}

// async global->LDS, 16B per lane (wave-uniform base + lane*16 matches linear dest).
__device__ __forceinline__ void gl_lds16(const unsigned short* g, unsigned short* l) {
    __builtin_amdgcn_global_load_lds(
        (const __attribute__((address_space(1))) unsigned int*)g,
        (__attribute__((address_space(3))) unsigned int*)l, 16, 0, 0);
}

// ---------------- QKV projection: C = X @ W^T + b, both operands fp32->bf16 on the fly ------
// BM=128, BN=128. grid (192, 3). XCD-coherent map (same-A blocks share an XCD).
// No separate weight-cvt kernel: W is reg-staged fp32->bf16 exactly like A.
__global__ __launch_bounds__(256) void gemm_qkv_kernel(
    const float* Xq, const float* Xk, const float* Xv,
    const float* W0, const float* W1, const float* W2,
    const float* b0, const float* b1, const float* b2, unsigned short* qh)
{
    int by = blockIdx.y;
    const float* A = (by == 0) ? Xq : (by == 1) ? Xk : Xv;
    const float* W = (by == 0) ? W0 : (by == 1) ? W1 : W2;
    const float* bias = (by == 0) ? b0 : (by == 1) ? b1 : b2;
    int bx = blockIdx.x;
    int im = (bx & 7) + 8 * (bx / 48);    // 32 M tiles of 128; im%8 == bx%8 (same XCD)
    int jn = (bx >> 3) % 6;               // 6 N tiles of 128
    int i0 = im * 128, j0 = jn * 128;

    __shared__ unsigned short As[128 * 64];   // 16KB
    __shared__ unsigned short Ws[128 * 64];   // 16KB

    int t = threadIdx.x;
    int w = t >> 6, lane = t & 63, g = lane >> 4, fr = lane & 15;
    int wm = w >> 1, wn = w & 1;              // wave tile 64 x 64

    f32x4 acc[4][4];
    for (int i = 0; i < 4; ++i)
        for (int j = 0; j < 4; ++j)
            acc[i][j] = (f32x4){0.f, 0.f, 0.f, 0.f};

    int arow = t >> 3;          // staging: 32 rows/round, 8 threads/row
    int acol = (t & 7) * 8;     // 8 floats per thread

    for (int k0 = 0; k0 < DM; k0 += 64) {
        __syncthreads();
        for (int rr = 0; rr < 4; ++rr) {
            int row = rr * 32 + arow;
            const float* srca = &A[(size_t)(i0 + row) * DM + k0 + acol];
            f32x4 v0 = *(const f32x4*)srca;
            f32x4 v1 = *(const f32x4*)(srca + 4);
            short8 o;
            o[0] = (short)f2bf(v0[0]); o[1] = (short)f2bf(v0[1]);
            o[2] = (short)f2bf(v0[2]); o[3] = (short)f2bf(v0[3]);
            o[4] = (short)f2bf(v1[0]); o[5] = (short)f2bf(v1[1]);
            o[6] = (short)f2bf(v1[2]); o[7] = (short)f2bf(v1[3]);
            *(short8*)&As[row * 64 + acol] = o;
            const float* srcw = &W[(size_t)(j0 + row) * DM + k0 + acol];
            f32x4 w0v = *(const f32x4*)srcw;
            f32x4 w1v = *(const f32x4*)(srcw + 4);
            short8 ow;
            ow[0] = (short)f2bf(w0v[0]); ow[1] = (short)f2bf(w0v[1]);
            ow[2] = (short)f2bf(w0v[2]); ow[3] = (short)f2bf(w0v[3]);
            ow[4] = (short)f2bf(w1v[0]); ow[5] = (short)f2bf(w1v[1]);
            ow[6] = (short)f2bf(w1v[2]); ow[7] = (short)f2bf(w1v[3]);
            *(short8*)&Ws[row * 64 + acol] = ow;
        }
        __syncthreads();
        for (int kk = 0; kk < 2; ++kk) {
            short8 af[4], wf[4];
            for (int it = 0; it < 4; ++it)
                af[it] = *(const short8*)&As[(wm * 64 + it * 16 + fr) * 64 + kk * 32 + g * 8];
            for (int jt = 0; jt < 4; ++jt)
                wf[jt] = *(const short8*)&Ws[(wn * 64 + jt * 16 + fr) * 64 + kk * 32 + g * 8];
            for (int it = 0; it < 4; ++it)
                for (int jt = 0; jt < 4; ++jt)
                    acc[it][jt] = __builtin_amdgcn_mfma_f32_16x16x32_bf16(af[it], wf[jt], acc[it][jt], 0, 0, 0);
        }
    }

    float scl = (by == 0) ? 0.125f : 1.0f;    // fold 1/sqrt(64) into q (exact)
    if (by < 2) {
        unsigned short* outp = qh + (size_t)by * XEL;   // head-split [b][h][s][64]
        for (int jt = 0; jt < 4; ++jt) {
            int j = j0 + wn * 64 + jt * 16 + fr;
            float bv = bias[j];
            int h = j >> 6, dq = j & 63;
            for (int it = 0; it < 4; ++it)
                for (int r = 0; r < 4; ++r) {
                    int i = i0 + wm * 64 + it * 16 + g * 4 + r;
                    int bb = i >> 11, s = i & 2047;
                    outp[((size_t)((bb * NH + h) * S_LEN) + s) * HD + dq] = f2bf((acc[it][jt][r] + bv) * scl);
                }
        }
    } else {
        unsigned short* vtp = qh + (size_t)2 * XEL;     // V transposed [bh][64][s]
        for (int jt = 0; jt < 4; ++jt) {
            int j = j0 + wn * 64 + jt * 16 + fr;
            float bv = bias[j];
            int h = j >> 6, dq = j & 63;
            for (int it = 0; it < 4; ++it) {
                int ibase = i0 + wm * 64 + it * 16 + g * 4;
                int bb = ibase >> 11, s = ibase & 2047;
                short4v o;
                for (int r = 0; r < 4; ++r) o[r] = (short)f2bf(acc[it][jt][r] + bv);
                *(short4v*)&vtp[((size_t)(bb * NH + h) * HD + dq) * S_LEN + s] = o;
            }
        }
    }
}

// ---------------- out projection: BM=64, BN=64, 768 blocks; W fp32 reg-staged ----------------
__global__ __launch_bounds__(256) void gemm_o_kernel(
    const unsigned short* A, const float* W, const float* bias, float* f_out)
{
    int bx = blockIdx.x;
    int im = (bx & 7) + 8 * (bx / 96);    // 64 M tiles of 64; same-A blocks share XCD
    int jn = (bx >> 3) % 12;              // 12 N tiles of 64
    int i0 = im * 64, j0 = jn * 64;

    __shared__ unsigned short As[64 * 64];    // 8KB
    __shared__ unsigned short Ws[64 * 64];    // 8KB

    int t = threadIdx.x;
    int w = t >> 6, lane = t & 63, g = lane >> 4, fr = lane & 15;
    int wm = w >> 1, wn = w & 1;              // wave tile 32 x 32

    f32x4 acc[2][2];
    for (int i = 0; i < 2; ++i)
        for (int j = 0; j < 2; ++j)
            acc[i][j] = (f32x4){0.f, 0.f, 0.f, 0.f};

    int boff = t * 16;
    int arow = t >> 3, acol = (t & 7) * 8;

    for (int k0 = 0; k0 < DM; k0 += 64) {
        __syncthreads();
        for (int r = 0; r < 2; ++r) {
            int b = r * 4096 + boff;
            int row = b >> 7, colb = b & 127;
            gl_lds16(&A[(size_t)(i0 + row) * DM + k0 + (colb >> 1)],
                     (unsigned short*)((char*)As + b));
        }
        for (int rr = 0; rr < 2; ++rr) {
            int row = rr * 32 + arow;
            const float* srcw = &W[(size_t)(j0 + row) * DM + k0 + acol];
            f32x4 w0v = *(const f32x4*)srcw;
            f32x4 w1v = *(const f32x4*)(srcw + 4);
            short8 ow;
            ow[0] = (short)f2bf(w0v[0]); ow[1] = (short)f2bf(w0v[1]);
            ow[2] = (short)f2bf(w0v[2]); ow[3] = (short)f2bf(w0v[3]);
            ow[4] = (short)f2bf(w1v[0]); ow[5] = (short)f2bf(w1v[1]);
            ow[6] = (short)f2bf(w1v[2]); ow[7] = (short)f2bf(w1v[3]);
            *(short8*)&Ws[row * 64 + acol] = ow;
        }
        __syncthreads();
        for (int kk = 0; kk < 2; ++kk) {
            short8 af[2], wf[2];
            for (int it = 0; it < 2; ++it)
                af[it] = *(const short8*)&As[(wm * 32 + it * 16 + fr) * 64 + kk * 32 + g * 8];
            for (int jt = 0; jt < 2; ++jt)
                wf[jt] = *(const short8*)&Ws[(wn * 32 + jt * 16 + fr) * 64 + kk * 32 + g * 8];
            for (int it = 0; it < 2; ++it)
                for (int jt = 0; jt < 2; ++jt)
                    acc[it][jt] = __builtin_amdgcn_mfma_f32_16x16x32_bf16(af[it], wf[jt], acc[it][jt], 0, 0, 0);
        }
    }

    for (int jt = 0; jt < 2; ++jt) {
        int j = j0 + wn * 32 + jt * 16 + fr;
        float bv = bias[j];
        for (int it = 0; it < 2; ++it)
            for (int r = 0; r < 4; ++r) {
                int i = i0 + wm * 32 + it * 16 + g * 4 + r;
                f_out[(size_t)i * DM + j] = acc[it][jt][r] + bv;
            }
    }
}

// ---------------- flash attention: K LDS-staged (dbuf), V direct from L2, 4 blocks/CU -------
// 768 blocks = 24 bh x 32 span-pairs (waves 0,1: span s; waves 2,3: span 63-s; uniform stores).
// R8 structure, two changes:
//  (1) only K is staged (dbuf 2x8KB, swizzled); V^T frags are plain 16B global loads served
//      by the XCD-local L2 (bh pinned to XCD; V working set 1.5MB/XCD). LDS/block 33KB ->
//      4 blocks/CU = 16 waves (was 3/12), and per-tile staging volume halves.
//  (2) __launch_bounds__(256,4) to hold 4 blocks/CU.
__global__ __launch_bounds__(256, 4) void attn_kernel(
    const unsigned short* q, const unsigned short* k, const unsigned short* vt,
    float* scores, unsigned short* attn)
{
    __shared__ unsigned short Ks[2][4096];   // dbuf K tile 64x64 bf16 (swizzled), 8KB each
    __shared__ float P[4][16][68];           // 17.4KB
    int t = threadIdx.x;
    int w = t >> 6, lane = t & 63, g = lane >> 4, fr = lane & 15;
    float (*Pw)[68] = P[w];

    int bid = blockIdx.x;
    int bh = (bid & 7) * 3 + (bid >> 3) % 3;   // bh tied to XCD (K/V L2 locality)
    int s = bid / 24;                          // 0..31 pair index
    int myspan = (w < 2) ? s : 63 - s;
    int qbase = myspan * 32 + (w & 1) * 16;
    int myNt = ((myspan * 32 + 31) >> 6) + 1;
    int ntmax = (((63 - s) * 32 + 31) >> 6) + 1;
    int b = bh / NH, h = bh % NH;

    const unsigned short* qp = q + (size_t)bh * S_LEN * HD;
    const unsigned short* kp = k + (size_t)bh * S_LEN * HD;
    const unsigned short* vp = vt + (size_t)bh * HD * S_LEN;
    float* sp = scores + (size_t)bh * S_LEN * S_LEN;

    int srow2 = t >> 3;                 // 0..31
    int scb = (t & 7) * 16;             // byte col in 128B row
    int swzu = (fr & 7) * 8;            // frag-read swizzle in ushort units

    short8 qf0 = *(const short8*)&qp[(size_t)(qbase + fr) * HD + g * 8];
    short8 qf1 = *(const short8*)&qp[(size_t)(qbase + fr) * HD + 32 + g * 8];

    f32x4 acc[4];
    for (int jt = 0; jt < 4; ++jt) acc[jt] = (f32x4){0.f, 0.f, 0.f, 0.f};
    float m_run = -1e30f, l_run = 0.f;

    // prologue: stage K tile 0 into buf 0 (pre-swizzled global source, linear LDS dest)
    for (int rd = 0; rd < 2; ++rd) {
        int row = rd * 32 + srow2;
        int sc = (scb ^ ((row & 7) << 4)) >> 1;
        gl_lds16(&kp[(size_t)row * HD + sc], &Ks[0][(size_t)t * 8 + rd * 2048]);
    }

    int buf = 0;
    for (int kt = 0; kt < ntmax; ++kt) {
        __syncthreads();   // staging of tile kt complete; prev compute's LDS reads done
        if (kt + 1 < ntmax) {
            int kb2 = (kt + 1) * 64;
            for (int rd = 0; rd < 2; ++rd) {
                int row = rd * 32 + srow2;
                int sc = (scb ^ ((row & 7) << 4)) >> 1;
                gl_lds16(&kp[(size_t)(kb2 + row) * HD + sc], &Ks[buf ^ 1][(size_t)t * 8 + rd * 2048]);
            }
        }
        if (kt < myNt) {
            const unsigned short* Kb = Ks[buf];
            int kb = kt * 64;
            bool diag = (kt == myNt - 1);

            short8 kf[4][2];
            for (int ktt = 0; ktt < 4; ++ktt) {
                int base = (ktt * 16 + fr) * 64;
                kf[ktt][0] = *(const short8*)&Kb[base + ((g * 8) ^ swzu)];
                kf[ktt][1] = *(const short8*)&Kb[base + ((32 + g * 8) ^ swzu)];
            }
            __builtin_amdgcn_s_setprio(1);
            f32x4 s4v[4];
            for (int ktt = 0; ktt < 4; ++ktt) {
                f32x4 s4 = (f32x4){0.f, 0.f, 0.f, 0.f};
                s4 = __builtin_amdgcn_mfma_f32_16x16x32_bf16(qf0, kf[ktt][0], s4, 0, 0, 0);
                s4 = __builtin_amdgcn_mfma_f32_16x16x32_bf16(qf1, kf[ktt][1], s4, 0, 0, 0);
                s4v[ktt] = s4;
            }
            __builtin_amdgcn_s_setprio(0);
            if (diag) {
                for (int ktt = 0; ktt < 4; ++ktt) {
                    int kg = kb + ktt * 16 + fr;     // C col = k index
                    for (int r = 0; r < 4; ++r) {
                        int qg = qbase + g * 4 + r;  // C row = q index
                        float val = (kg <= qg) ? s4v[ktt][r] : NEGINF;
                        Pw[g * 4 + r][ktt * 16 + fr] = val;
                    }
                }
            } else {
                for (int ktt = 0; ktt < 4; ++ktt)
                    for (int r = 0; r < 4; ++r)
                        Pw[g * 4 + r][ktt * 16 + fr] = s4v[ktt][r];
            }
            // coalesced nontemporal scores write (16 rows x 64 cols fp32; 256B row segments)
            for (int pass = 0; pass < 4; ++pass) {
                int rr = pass * 4 + g;
                int cc = fr * 4;
                f32x4 vv = *(const f32x4*)&Pw[rr][cc];
                __builtin_nontemporal_store(vv, (f32x4*)&sp[(size_t)(qbase + rr) * S_LEN + kb + cc]);
            }
            // online softmax in A-frag layout (lane owns q-row fr); vector LDS reads
            f32x4 pA = *(const f32x4*)&Pw[fr][g * 8];
            f32x4 pB = *(const f32x4*)&Pw[fr][g * 8 + 4];
            f32x4 pC = *(const f32x4*)&Pw[fr][32 + g * 8];
            f32x4 pD = *(const f32x4*)&Pw[fr][32 + g * 8 + 4];
            float pv[16];
            pv[0]=pA[0]; pv[1]=pA[1]; pv[2]=pA[2]; pv[3]=pA[3];
            pv[4]=pB[0]; pv[5]=pB[1]; pv[6]=pB[2]; pv[7]=pB[3];
            pv[8]=pC[0]; pv[9]=pC[1]; pv[10]=pC[2]; pv[11]=pC[3];
            pv[12]=pD[0]; pv[13]=pD[1]; pv[14]=pD[2]; pv[15]=pD[3];
            float tmax = pv[0];
            for (int e = 1; e < 16; ++e) tmax = fmaxf(tmax, pv[e]);
            tmax = fmaxf(tmax, __shfl_xor(tmax, 16, 64));
            tmax = fmaxf(tmax, __shfl_xor(tmax, 32, 64));
            float m_new = fmaxf(m_run, tmax);
            float corr = __expf(m_run - m_new);
            float lsum = 0.f;
            for (int e = 0; e < 16; ++e) { pv[e] = __expf(pv[e] - m_new); lsum += pv[e]; }
            lsum += __shfl_xor(lsum, 16, 64);
            lsum += __shfl_xor(lsum, 32, 64);
            l_run = l_run * corr + lsum;
            m_run = m_new;
            short8 pa0, pa1;
            for (int e = 0; e < 8; ++e) { pa0[e] = (short)f2bf(pv[e]); pa1[e] = (short)f2bf(pv[8 + e]); }
            float fc[4];
            for (int r = 0; r < 4; ++r) fc[r] = __shfl(corr, g * 4 + r, 64);
            for (int jt = 0; jt < 4; ++jt)
                for (int r = 0; r < 4; ++r) acc[jt][r] *= fc[r];
            // V^T fragments direct from L2 (row = d, 16B per lane; 64B/row per instr)
            short8 vf[4][2];
            for (int jt = 0; jt < 4; ++jt) {
                vf[jt][0] = *(const short8*)&vp[(size_t)(jt * 16 + fr) * S_LEN + kb + g * 8];
                vf[jt][1] = *(const short8*)&vp[(size_t)(jt * 16 + fr) * S_LEN + kb + 32 + g * 8];
            }
            __builtin_amdgcn_s_setprio(1);
            for (int jt = 0; jt < 4; ++jt) {
                acc[jt] = __builtin_amdgcn_mfma_f32_16x16x32_bf16(pa0, vf[jt][0], acc[jt], 0, 0, 0);
                acc[jt] = __builtin_amdgcn_mfma_f32_16x16x32_bf16(pa1, vf[jt][1], acc[jt], 0, 0, 0);
            }
            __builtin_amdgcn_s_setprio(0);
        }
        buf ^= 1;
    }
    // epilogue: divide by l, write attn bf16 [4096][768]
    float linv[4];
    for (int r = 0; r < 4; ++r) linv[r] = 1.0f / __shfl(l_run, g * 4 + r, 64);
    for (int jt = 0; jt < 4; ++jt) {
        int col = h * HD + jt * 16 + fr;
        for (int r = 0; r < 4; ++r) {
            int i = b * S_LEN + qbase + g * 4 + r;
            attn[(size_t)i * DM + col] = f2bf(acc[jt][r] * linv[r]);
        }
    }
    // NEG_INF fill for this wave's fully masked region
    f32x4 nv = (f32x4){NEGINF, NEGINF, NEGINF, NEGINF};
    int fill0 = myNt * 64;
    for (int rr = 0; rr < 16; ++rr) {
        float* rowp = &sp[(size_t)(qbase + rr) * S_LEN];
        for (int c = fill0 + lane * 4; c < S_LEN; c += 256)
            __builtin_nontemporal_store(nv, (f32x4*)(rowp + c));
    }
}

extern "C" void kernel_launch(void* const* d_in, const int* in_sizes, int n_in,
                              void* d_out, int out_size, void* d_ws, size_t ws_size,
                              hipStream_t stream) {
    const float* Q  = (const float*)d_in[0];
    const float* K  = (const float*)d_in[1];
    const float* V  = (const float*)d_in[2];
    // d_in[3] = mask (causal tril) — recomputed analytically, not read
    const float* Wq = (const float*)d_in[4];
    const float* bq = (const float*)d_in[5];
    const float* Wk = (const float*)d_in[6];
    const float* bk = (const float*)d_in[7];
    const float* Wv = (const float*)d_in[8];
    const float* bv = (const float*)d_in[9];
    const float* Wo = (const float*)d_in[10];
    const float* bo = (const float*)d_in[11];

    float* out = (float*)d_out;
    float* scores = out + (size_t)MROWS * DM;

    unsigned short* ws    = (unsigned short*)d_ws;
    unsigned short* qh    = ws;                             // XEL q + XEL k (head-split) + XEL vt
    unsigned short* attnb = qh + (size_t)3 * XEL;           // XEL attn bf16

    gemm_qkv_kernel<<<dim3(192, 3), 256, 0, stream>>>(Q, K, V, Wq, Wk, Wv, bq, bk, bv, qh);
    attn_kernel<<<dim3(768), 256, 0, stream>>>(qh, qh + (size_t)XEL, qh + (size_t)2 * XEL,
                                               scores, attnb);
    gemm_o_kernel<<<dim3(768), 256, 0, stream>>>(attnb, Wo, bo, out);
}

// Round 13
// 154.741 us; speedup vs baseline: 1.1713x; 1.1713x over previous
//
#include <hip/hip_runtime.h>
#include <hip/hip_bf16.h>

typedef __attribute__((ext_vector_type(8))) short short8;
typedef __attribute__((ext_vector_type(4))) short short4v;
typedef __attribute__((ext_vector_type(4))) float f32x4;

#define S_LEN 2048
#define DM 768
#define NH 12
#define HD 64
#define NB 2
#define MROWS (NB*S_LEN)          // 4096
#define NEGINF (-1.0e9f)
#define XEL 3145728               // 4096*768 elements
#define WEL 589824                // 768*768

__device__ __forceinline__ unsigned short f2bf(float x) {
    __hip_bfloat16 h = __float2bfloat16(x);   // RNE; compiler pairs into v_cvt_pk_bf16_f32
    return *reinterpret_cast<unsigned short*>(&h);
}

// async global->LDS, 16B per lane (wave-uniform base + lane*16 matches linear dest).
__device__ __forceinline__ void gl_lds16(const unsigned short* g, unsigned short* l) {
    __builtin_amdgcn_global_load_lds(
        (const __attribute__((address_space(1))) unsigned int*)g,
        (__attribute__((address_space(3))) unsigned int*)l, 16, 0, 0);
}

// ---------------- weights fp32 -> bf16 ----------------
__global__ __launch_bounds__(256) void cvt_w_kernel(
    const float* w0, const float* w1, const float* w2, const float* w3,
    unsigned short* dst)
{
    int which = blockIdx.y;
    const float* src = (which == 0) ? w0 : (which == 1) ? w1 : (which == 2) ? w2 : w3;
    size_t idx = (size_t)blockIdx.x * 256 + threadIdx.x;   // 0 .. WEL/8-1
    const float* s = src + idx * 8;
    f32x4 v0 = *(const f32x4*)s;
    f32x4 v1 = *(const f32x4*)(s + 4);
    short8 o;
    o[0] = (short)f2bf(v0[0]); o[1] = (short)f2bf(v0[1]);
    o[2] = (short)f2bf(v0[2]); o[3] = (short)f2bf(v0[3]);
    o[4] = (short)f2bf(v1[0]); o[5] = (short)f2bf(v1[1]);
    o[6] = (short)f2bf(v1[2]); o[7] = (short)f2bf(v1[3]);
    *(short8*)&dst[(size_t)which * WEL + idx * 8] = o;
}

// ---------------- QKV projection: C = X @ W^T + b, fused fp32->bf16 A-staging ----------------
// BM=128, BN=128. grid (192, 3). XCD-coherent map (same-A blocks share an XCD).
__global__ __launch_bounds__(256) void gemm_qkv_kernel(
    const float* Xq, const float* Xk, const float* Xv, const unsigned short* Wall,
    const float* b0, const float* b1, const float* b2, unsigned short* qh)
{
    int by = blockIdx.y;
    const float* A = (by == 0) ? Xq : (by == 1) ? Xk : Xv;
    const unsigned short* W = Wall + (size_t)by * WEL;
    const float* bias = (by == 0) ? b0 : (by == 1) ? b1 : b2;
    int bx = blockIdx.x;
    int im = (bx & 7) + 8 * (bx / 48);    // 32 M tiles of 128; im%8 == bx%8 (same XCD)
    int jn = (bx >> 3) % 6;               // 6 N tiles of 128
    int i0 = im * 128, j0 = jn * 128;

    __shared__ unsigned short As[128 * 64];   // 16KB
    __shared__ unsigned short Ws[128 * 64];   // 16KB

    int t = threadIdx.x;
    int w = t >> 6, lane = t & 63, g = lane >> 4, fr = lane & 15;
    int wm = w >> 1, wn = w & 1;              // wave tile 64 x 64

    f32x4 acc[4][4];
    for (int i = 0; i < 4; ++i)
        for (int j = 0; j < 4; ++j)
            acc[i][j] = (f32x4){0.f, 0.f, 0.f, 0.f};

    int boff = t * 16;          // W staging byte offset per 4KB round
    int arow = t >> 3;          // A staging: 32 rows/round, 8 threads/row
    int acol = (t & 7) * 8;     // 8 floats per thread

    for (int k0 = 0; k0 < DM; k0 += 64) {
        __syncthreads();
        for (int r = 0; r < 4; ++r) {
            int b = r * 4096 + boff;
            int row = b >> 7, colb = b & 127;
            gl_lds16(&W[(size_t)(j0 + row) * DM + k0 + (colb >> 1)],
                     (unsigned short*)((char*)Ws + b));
        }
        for (int rr = 0; rr < 4; ++rr) {
            int row = rr * 32 + arow;
            const float* src = &A[(size_t)(i0 + row) * DM + k0 + acol];
            f32x4 v0 = *(const f32x4*)src;
            f32x4 v1 = *(const f32x4*)(src + 4);
            short8 o;
            o[0] = (short)f2bf(v0[0]); o[1] = (short)f2bf(v0[1]);
            o[2] = (short)f2bf(v0[2]); o[3] = (short)f2bf(v0[3]);
            o[4] = (short)f2bf(v1[0]); o[5] = (short)f2bf(v1[1]);
            o[6] = (short)f2bf(v1[2]); o[7] = (short)f2bf(v1[3]);
            *(short8*)&As[row * 64 + acol] = o;
        }
        __syncthreads();
        for (int kk = 0; kk < 2; ++kk) {
            short8 af[4], wf[4];
            for (int it = 0; it < 4; ++it)
                af[it] = *(const short8*)&As[(wm * 64 + it * 16 + fr) * 64 + kk * 32 + g * 8];
            for (int jt = 0; jt < 4; ++jt)
                wf[jt] = *(const short8*)&Ws[(wn * 64 + jt * 16 + fr) * 64 + kk * 32 + g * 8];
            for (int it = 0; it < 4; ++it)
                for (int jt = 0; jt < 4; ++jt)
                    acc[it][jt] = __builtin_amdgcn_mfma_f32_16x16x32_bf16(af[it], wf[jt], acc[it][jt], 0, 0, 0);
        }
    }

    float scl = (by == 0) ? 0.125f : 1.0f;    // fold 1/sqrt(64) into q (exact)
    if (by < 2) {
        unsigned short* outp = qh + (size_t)by * XEL;   // head-split [b][h][s][64]
        for (int jt = 0; jt < 4; ++jt) {
            int j = j0 + wn * 64 + jt * 16 + fr;
            float bv = bias[j];
            int h = j >> 6, dq = j & 63;
            for (int it = 0; it < 4; ++it)
                for (int r = 0; r < 4; ++r) {
                    int i = i0 + wm * 64 + it * 16 + g * 4 + r;
                    int bb = i >> 11, s = i & 2047;
                    outp[((size_t)((bb * NH + h) * S_LEN) + s) * HD + dq] = f2bf((acc[it][jt][r] + bv) * scl);
                }
        }
    } else {
        unsigned short* vtp = qh + (size_t)2 * XEL;     // V transposed [bh][64][s]
        for (int jt = 0; jt < 4; ++jt) {
            int j = j0 + wn * 64 + jt * 16 + fr;
            float bv = bias[j];
            int h = j >> 6, dq = j & 63;
            for (int it = 0; it < 4; ++it) {
                int ibase = i0 + wm * 64 + it * 16 + g * 4;
                int bb = ibase >> 11, s = ibase & 2047;
                short4v o;
                for (int r = 0; r < 4; ++r) o[r] = (short)f2bf(acc[it][jt][r] + bv);
                *(short4v*)&vtp[((size_t)(bb * NH + h) * HD + dq) * S_LEN + s] = o;
            }
        }
    }
}

// ---------------- out projection: BM=64, BN=64, 768 blocks, XCD-coherent map ----------------
__global__ __launch_bounds__(256) void gemm_o_kernel(
    const unsigned short* A, const unsigned short* W, const float* bias, float* f_out)
{
    int bx = blockIdx.x;
    int im = (bx & 7) + 8 * (bx / 96);    // 64 M tiles of 64; same-A blocks share XCD
    int jn = (bx >> 3) % 12;              // 12 N tiles of 64
    int i0 = im * 64, j0 = jn * 64;

    __shared__ unsigned short As[64 * 64];    // 8KB
    __shared__ unsigned short Ws[64 * 64];    // 8KB

    int t = threadIdx.x;
    int w = t >> 6, lane = t & 63, g = lane >> 4, fr = lane & 15;
    int wm = w >> 1, wn = w & 1;              // wave tile 32 x 32

    f32x4 acc[2][2];
    for (int i = 0; i < 2; ++i)
        for (int j = 0; j < 2; ++j)
            acc[i][j] = (f32x4){0.f, 0.f, 0.f, 0.f};

    int boff = t * 16;

    for (int k0 = 0; k0 < DM; k0 += 64) {
        __syncthreads();
        for (int r = 0; r < 2; ++r) {
            int b = r * 4096 + boff;
            int row = b >> 7, colb = b & 127;
            gl_lds16(&A[(size_t)(i0 + row) * DM + k0 + (colb >> 1)],
                     (unsigned short*)((char*)As + b));
            gl_lds16(&W[(size_t)(j0 + row) * DM + k0 + (colb >> 1)],
                     (unsigned short*)((char*)Ws + b));
        }
        __syncthreads();
        for (int kk = 0; kk < 2; ++kk) {
            short8 af[2], wf[2];
            for (int it = 0; it < 2; ++it)
                af[it] = *(const short8*)&As[(wm * 32 + it * 16 + fr) * 64 + kk * 32 + g * 8];
            for (int jt = 0; jt < 2; ++jt)
                wf[jt] = *(const short8*)&Ws[(wn * 32 + jt * 16 + fr) * 64 + kk * 32 + g * 8];
            for (int it = 0; it < 2; ++it)
                for (int jt = 0; jt < 2; ++jt)
                    acc[it][jt] = __builtin_amdgcn_mfma_f32_16x16x32_bf16(af[it], wf[jt], acc[it][jt], 0, 0, 0);
        }
    }

    for (int jt = 0; jt < 2; ++jt) {
        int j = j0 + wn * 32 + jt * 16 + fr;
        float bv = bias[j];
        for (int it = 0; it < 2; ++it)
            for (int r = 0; r < 4; ++r) {
                int i = i0 + wm * 32 + it * 16 + g * 4 + r;
                f_out[(size_t)i * DM + j] = acc[it][jt][r] + bv;
            }
    }
}

// ---------------- flash attention (R8 structure) + idle-slot NEG_INF fill ----------------
// 768 blocks = 24 bh x 32 span-pairs (waves 0,1: span s; waves 2,3: span 63-s).
// K/V double-buffered swizzled LDS, staged once per block; stores uniform per block.
// NEW vs R8: light waves use their idle barrier iterations (kt >= myNt) to issue 2 rows of
// NEG_INF fill each — converting convoy dead time into store-pipe work that overlaps heavy
// waves' compute. Fill remaining after the loop is written in the epilogue as before.
__global__ __launch_bounds__(256) void attn_kernel(
    const unsigned short* q, const unsigned short* k, const unsigned short* vt,
    float* scores, unsigned short* attn)
{
    __shared__ unsigned short KV[2][8192];   // [buf][0..4095]=K tile, [4096..]=V^T tile (swizzled)
    __shared__ float P[4][16][68];
    int t = threadIdx.x;
    int w = t >> 6, lane = t & 63, g = lane >> 4, fr = lane & 15;
    float (*Pw)[68] = P[w];

    int bid = blockIdx.x;
    int bh = (bid & 7) * 3 + (bid >> 3) % 3;   // bh tied to XCD (K/V L2 locality)
    int s = bid / 24;                          // 0..31 pair index
    int myspan = (w < 2) ? s : 63 - s;
    int qbase = myspan * 32 + (w & 1) * 16;
    int myNt = ((myspan * 32 + 31) >> 6) + 1;
    int ntmax = (((63 - s) * 32 + 31) >> 6) + 1;
    int b = bh / NH, h = bh % NH;

    const unsigned short* qp = q + (size_t)bh * S_LEN * HD;
    const unsigned short* kp = k + (size_t)bh * S_LEN * HD;
    const unsigned short* vp = vt + (size_t)bh * HD * S_LEN;
    float* sp = scores + (size_t)bh * S_LEN * S_LEN;

    int srow2 = t >> 3;                 // 0..31
    int scb = (t & 7) * 16;             // byte col in 128B row
    int swzu = (fr & 7) * 8;            // frag-read swizzle in ushort units

    short8 qf0 = *(const short8*)&qp[(size_t)(qbase + fr) * HD + g * 8];
    short8 qf1 = *(const short8*)&qp[(size_t)(qbase + fr) * HD + 32 + g * 8];

    f32x4 acc[4];
    for (int jt = 0; jt < 4; ++jt) acc[jt] = (f32x4){0.f, 0.f, 0.f, 0.f};
    float m_run = -1e30f, l_run = 0.f;

    // idle-slot fill state
    f32x4 nv = (f32x4){NEGINF, NEGINF, NEGINF, NEGINF};
    int fill0 = myNt * 64;              // first strictly-masked col for this wave's rows
    int fillRow = 0;                    // next row (0..15) to fill in an idle slot

    // prologue stage tile 0 into buf 0 (pre-swizzled global source, linear LDS dest)
    for (int rd = 0; rd < 2; ++rd) {
        int row = rd * 32 + srow2;
        int sc = (scb ^ ((row & 7) << 4)) >> 1;
        gl_lds16(&kp[(size_t)row * HD + sc], &KV[0][(size_t)t * 8 + rd * 2048]);
        gl_lds16(&vp[(size_t)row * S_LEN + sc], &KV[0][4096 + (size_t)t * 8 + rd * 2048]);
    }

    int buf = 0;
    for (int kt = 0; kt < ntmax; ++kt) {
        __syncthreads();   // staging of tile kt complete; prev compute's LDS reads done
        if (kt + 1 < ntmax) {
            int kb2 = (kt + 1) * 64;
            for (int rd = 0; rd < 2; ++rd) {
                int row = rd * 32 + srow2;
                int sc = (scb ^ ((row & 7) << 4)) >> 1;
                gl_lds16(&kp[(size_t)(kb2 + row) * HD + sc], &KV[buf ^ 1][(size_t)t * 8 + rd * 2048]);
                gl_lds16(&vp[(size_t)row * S_LEN + kb2 + sc], &KV[buf ^ 1][4096 + (size_t)t * 8 + rd * 2048]);
            }
        }
        if (kt < myNt) {
            const unsigned short* Kb = KV[buf];
            const unsigned short* Vb = KV[buf] + 4096;
            int kb = kt * 64;
            bool diag = (kt == myNt - 1);

            short8 kf[4][2];
            for (int ktt = 0; ktt < 4; ++ktt) {
                int base = (ktt * 16 + fr) * 64;
                kf[ktt][0] = *(const short8*)&Kb[base + ((g * 8) ^ swzu)];
                kf[ktt][1] = *(const short8*)&Kb[base + ((32 + g * 8) ^ swzu)];
            }
            __builtin_amdgcn_s_setprio(1);
            f32x4 s4v[4];
            for (int ktt = 0; ktt < 4; ++ktt) {
                f32x4 s4 = (f32x4){0.f, 0.f, 0.f, 0.f};
                s4 = __builtin_amdgcn_mfma_f32_16x16x32_bf16(qf0, kf[ktt][0], s4, 0, 0, 0);
                s4 = __builtin_amdgcn_mfma_f32_16x16x32_bf16(qf1, kf[ktt][1], s4, 0, 0, 0);
                s4v[ktt] = s4;
            }
            __builtin_amdgcn_s_setprio(0);
            if (diag) {
                for (int ktt = 0; ktt < 4; ++ktt) {
                    int kg = kb + ktt * 16 + fr;     // C col = k index
                    for (int r = 0; r < 4; ++r) {
                        int qg = qbase + g * 4 + r;  // C row = q index
                        float val = (kg <= qg) ? s4v[ktt][r] : NEGINF;
                        Pw[g * 4 + r][ktt * 16 + fr] = val;
                    }
                }
            } else {
                for (int ktt = 0; ktt < 4; ++ktt)
                    for (int r = 0; r < 4; ++r)
                        Pw[g * 4 + r][ktt * 16 + fr] = s4v[ktt][r];
            }
            // coalesced nontemporal scores write (16 rows x 64 cols fp32)
            for (int pass = 0; pass < 4; ++pass) {
                int rr = pass * 4 + g;
                int cc = fr * 4;
                f32x4 vv = *(const f32x4*)&Pw[rr][cc];
                __builtin_nontemporal_store(vv, (f32x4*)&sp[(size_t)(qbase + rr) * S_LEN + kb + cc]);
            }
            // online softmax in A-frag layout (lane owns q-row fr); vector LDS reads
            f32x4 pA = *(const f32x4*)&Pw[fr][g * 8];
            f32x4 pB = *(const f32x4*)&Pw[fr][g * 8 + 4];
            f32x4 pC = *(const f32x4*)&Pw[fr][32 + g * 8];
            f32x4 pD = *(const f32x4*)&Pw[fr][32 + g * 8 + 4];
            float pv[16];
            pv[0]=pA[0]; pv[1]=pA[1]; pv[2]=pA[2]; pv[3]=pA[3];
            pv[4]=pB[0]; pv[5]=pB[1]; pv[6]=pB[2]; pv[7]=pB[3];
            pv[8]=pC[0]; pv[9]=pC[1]; pv[10]=pC[2]; pv[11]=pC[3];
            pv[12]=pD[0]; pv[13]=pD[1]; pv[14]=pD[2]; pv[15]=pD[3];
            float tmax = pv[0];
            for (int e = 1; e < 16; ++e) tmax = fmaxf(tmax, pv[e]);
            tmax = fmaxf(tmax, __shfl_xor(tmax, 16, 64));
            tmax = fmaxf(tmax, __shfl_xor(tmax, 32, 64));
            float m_new = fmaxf(m_run, tmax);
            float corr = __expf(m_run - m_new);
            float lsum = 0.f;
            for (int e = 0; e < 16; ++e) { pv[e] = __expf(pv[e] - m_new); lsum += pv[e]; }
            lsum += __shfl_xor(lsum, 16, 64);
            lsum += __shfl_xor(lsum, 32, 64);
            l_run = l_run * corr + lsum;
            m_run = m_new;
            short8 pa0, pa1;
            for (int e = 0; e < 8; ++e) { pa0[e] = (short)f2bf(pv[e]); pa1[e] = (short)f2bf(pv[8 + e]); }
            float fc[4];
            for (int r = 0; r < 4; ++r) fc[r] = __shfl(corr, g * 4 + r, 64);
            for (int jt = 0; jt < 4; ++jt)
                for (int r = 0; r < 4; ++r) acc[jt][r] *= fc[r];
            short8 vf[4][2];
            for (int jt = 0; jt < 4; ++jt) {
                int base = (jt * 16 + fr) * 64;
                vf[jt][0] = *(const short8*)&Vb[base + ((g * 8) ^ swzu)];
                vf[jt][1] = *(const short8*)&Vb[base + ((32 + g * 8) ^ swzu)];
            }
            __builtin_amdgcn_s_setprio(1);
            for (int jt = 0; jt < 4; ++jt) {
                acc[jt] = __builtin_amdgcn_mfma_f32_16x16x32_bf16(pa0, vf[jt][0], acc[jt], 0, 0, 0);
                acc[jt] = __builtin_amdgcn_mfma_f32_16x16x32_bf16(pa1, vf[jt][1], acc[jt], 0, 0, 0);
            }
            __builtin_amdgcn_s_setprio(0);
        } else {
            // idle slot (light wave done computing): issue 2 rows of NEG_INF fill
            for (int rr = fillRow; rr < fillRow + 2 && rr < 16; ++rr) {
                float* rowp = &sp[(size_t)(qbase + rr) * S_LEN];
                for (int c = fill0 + lane * 4; c < S_LEN; c += 256)
                    __builtin_nontemporal_store(nv, (f32x4*)(rowp + c));
            }
            fillRow += 2;
        }
        buf ^= 1;
    }
    // epilogue: divide by l, write attn bf16 [4096][768]
    float linv[4];
    for (int r = 0; r < 4; ++r) linv[r] = 1.0f / __shfl(l_run, g * 4 + r, 64);
    for (int jt = 0; jt < 4; ++jt) {
        int col = h * HD + jt * 16 + fr;
        for (int r = 0; r < 4; ++r) {
            int i = b * S_LEN + qbase + g * 4 + r;
            attn[(size_t)i * DM + col] = f2bf(acc[jt][r] * linv[r]);
        }
    }
    // NEG_INF fill for rows not covered by idle slots
    for (int rr = (fillRow < 16 ? fillRow : 16); rr < 16; ++rr) {
        float* rowp = &sp[(size_t)(qbase + rr) * S_LEN];
        for (int c = fill0 + lane * 4; c < S_LEN; c += 256)
            __builtin_nontemporal_store(nv, (f32x4*)(rowp + c));
    }
}

extern "C" void kernel_launch(void* const* d_in, const int* in_sizes, int n_in,
                              void* d_out, int out_size, void* d_ws, size_t ws_size,
                              hipStream_t stream) {
    const float* Q  = (const float*)d_in[0];
    const float* K  = (const float*)d_in[1];
    const float* V  = (const float*)d_in[2];
    // d_in[3] = mask (causal tril) — recomputed analytically, not read
    const float* Wq = (const float*)d_in[4];
    const float* bq = (const float*)d_in[5];
    const float* Wk = (const float*)d_in[6];
    const float* bk = (const float*)d_in[7];
    const float* Wv = (const float*)d_in[8];
    const float* bv = (const float*)d_in[9];
    const float* Wo = (const float*)d_in[10];
    const float* bo = (const float*)d_in[11];

    float* out = (float*)d_out;
    float* scores = out + (size_t)MROWS * DM;

    unsigned short* ws   = (unsigned short*)d_ws;
    unsigned short* Wbf  = ws;                              // 4 * WEL  (Wq,Wk,Wv,Wo bf16)
    unsigned short* qh   = Wbf + (size_t)4 * WEL;           // XEL q + XEL k (head-split) + XEL vt
    unsigned short* attnb = qh + (size_t)3 * XEL;           // XEL attn bf16

    cvt_w_kernel<<<dim3(288, 4), 256, 0, stream>>>(Wq, Wk, Wv, Wo, Wbf);
    gemm_qkv_kernel<<<dim3(192, 3), 256, 0, stream>>>(Q, K, V, Wbf, bq, bk, bv, qh);
    attn_kernel<<<dim3(768), 256, 0, stream>>>(qh, qh + (size_t)XEL, qh + (size_t)2 * XEL,
                                               scores, attnb);
    gemm_o_kernel<<<dim3(768), 256, 0, stream>>>(attnb, Wbf + (size_t)3 * WEL, bo, out);
}

// Round 14
// 140.241 us; speedup vs baseline: 1.2924x; 1.1034x over previous
//
#include <hip/hip_runtime.h>
#include <hip/hip_bf16.h>

typedef __attribute__((ext_vector_type(8))) short short8;
typedef __attribute__((ext_vector_type(4))) short short4v;
typedef __attribute__((ext_vector_type(4))) float f32x4;

#define S_LEN 2048
#define DM 768
#define NH 12
#define HD 64
#define NB 2
#define MROWS (NB*S_LEN)          // 4096
#define NEGINF (-1.0e9f)
#define XEL 3145728               // 4096*768 elements
#define WEL 589824                // 768*768

__device__ __forceinline__ unsigned short f2bf(float x) {
    __hip_bfloat16 h = __float2bfloat16(x);   // RNE; compiler pairs into v_cvt_pk_bf16_f32
    return *reinterpret_cast<unsigned short*>(&h);
}

// async global->LDS, 16B per lane (wave-uniform base + lane*16 matches linear dest).
__device__ __forceinline__ void gl_lds16(const unsigned short* g, unsigned short* l) {
    __builtin_amdgcn_global_load_lds(
        (const __attribute__((address_space(1))) unsigned int*)g,
        (__attribute__((address_space(3))) unsigned int*)l, 16, 0, 0);
}

// ---------------- weights fp32 -> bf16 ----------------
__global__ __launch_bounds__(256) void cvt_w_kernel(
    const float* w0, const float* w1, const float* w2, const float* w3,
    unsigned short* dst)
{
    int which = blockIdx.y;
    const float* src = (which == 0) ? w0 : (which == 1) ? w1 : (which == 2) ? w2 : w3;
    size_t idx = (size_t)blockIdx.x * 256 + threadIdx.x;   // 0 .. WEL/8-1
    const float* s = src + idx * 8;
    f32x4 v0 = *(const f32x4*)s;
    f32x4 v1 = *(const f32x4*)(s + 4);
    short8 o;
    o[0] = (short)f2bf(v0[0]); o[1] = (short)f2bf(v0[1]);
    o[2] = (short)f2bf(v0[2]); o[3] = (short)f2bf(v0[3]);
    o[4] = (short)f2bf(v1[0]); o[5] = (short)f2bf(v1[1]);
    o[6] = (short)f2bf(v1[2]); o[7] = (short)f2bf(v1[3]);
    *(short8*)&dst[(size_t)which * WEL + idx * 8] = o;
}

// ---------------- QKV projection: C = X @ W^T + b, fused fp32->bf16 A-staging ----------------
// BM=128, BN=96. grid (256, 3) = 768 blocks = exactly 3/CU (was 2.25 -> ragged co-residency).
// XCD-coherent map: im%8 == bx%8 so blocks sharing an A M-tile land on one XCD.
__global__ __launch_bounds__(256) void gemm_qkv_kernel(
    const float* Xq, const float* Xk, const float* Xv, const unsigned short* Wall,
    const float* b0, const float* b1, const float* b2, unsigned short* qh)
{
    int by = blockIdx.y;
    const float* A = (by == 0) ? Xq : (by == 1) ? Xk : Xv;
    const unsigned short* W = Wall + (size_t)by * WEL;
    const float* bias = (by == 0) ? b0 : (by == 1) ? b1 : b2;
    int bx = blockIdx.x;
    int im = (bx & 7) + 8 * (bx >> 6);    // 32 M tiles of 128; im%8 == bx%8 (same XCD)
    int jn = (bx >> 3) & 7;               // 8 N tiles of 96
    int i0 = im * 128, j0 = jn * 96;

    __shared__ unsigned short As[128 * 64];   // 16KB
    __shared__ unsigned short Ws[96 * 64];    // 12KB

    int t = threadIdx.x;
    int w = t >> 6, lane = t & 63, g = lane >> 4, fr = lane & 15;
    int wm = w >> 1, wn = w & 1;              // wave tile 64 x 48

    f32x4 acc[4][3];
    for (int i = 0; i < 4; ++i)
        for (int j = 0; j < 3; ++j)
            acc[i][j] = (f32x4){0.f, 0.f, 0.f, 0.f};

    int boff = t * 16;          // W staging byte offset per 4KB round
    int arow = t >> 3;          // A staging: 32 rows/round, 8 threads/row
    int acol = (t & 7) * 8;     // 8 floats per thread

    for (int k0 = 0; k0 < DM; k0 += 64) {
        __syncthreads();
        for (int r = 0; r < 3; ++r) {                    // 96 rows = 3 x 4KB rounds
            int b = r * 4096 + boff;
            int row = b >> 7, colb = b & 127;
            gl_lds16(&W[(size_t)(j0 + row) * DM + k0 + (colb >> 1)],
                     (unsigned short*)((char*)Ws + b));
        }
        for (int rr = 0; rr < 4; ++rr) {
            int row = rr * 32 + arow;
            const float* src = &A[(size_t)(i0 + row) * DM + k0 + acol];
            f32x4 v0 = *(const f32x4*)src;
            f32x4 v1 = *(const f32x4*)(src + 4);
            short8 o;
            o[0] = (short)f2bf(v0[0]); o[1] = (short)f2bf(v0[1]);
            o[2] = (short)f2bf(v0[2]); o[3] = (short)f2bf(v0[3]);
            o[4] = (short)f2bf(v1[0]); o[5] = (short)f2bf(v1[1]);
            o[6] = (short)f2bf(v1[2]); o[7] = (short)f2bf(v1[3]);
            *(short8*)&As[row * 64 + acol] = o;
        }
        __syncthreads();
        for (int kk = 0; kk < 2; ++kk) {
            short8 af[4], wf[3];
            for (int it = 0; it < 4; ++it)
                af[it] = *(const short8*)&As[(wm * 64 + it * 16 + fr) * 64 + kk * 32 + g * 8];
            for (int jt = 0; jt < 3; ++jt)
                wf[jt] = *(const short8*)&Ws[(wn * 48 + jt * 16 + fr) * 64 + kk * 32 + g * 8];
            for (int it = 0; it < 4; ++it)
                for (int jt = 0; jt < 3; ++jt)
                    acc[it][jt] = __builtin_amdgcn_mfma_f32_16x16x32_bf16(af[it], wf[jt], acc[it][jt], 0, 0, 0);
        }
    }

    float scl = (by == 0) ? 0.125f : 1.0f;    // fold 1/sqrt(64) into q (exact)
    if (by < 2) {
        unsigned short* outp = qh + (size_t)by * XEL;   // head-split [b][h][s][64]
        for (int jt = 0; jt < 3; ++jt) {
            int j = j0 + wn * 48 + jt * 16 + fr;
            float bv = bias[j];
            int h = j >> 6, dq = j & 63;
            for (int it = 0; it < 4; ++it)
                for (int r = 0; r < 4; ++r) {
                    int i = i0 + wm * 64 + it * 16 + g * 4 + r;
                    int bb = i >> 11, s = i & 2047;
                    outp[((size_t)((bb * NH + h) * S_LEN) + s) * HD + dq] = f2bf((acc[it][jt][r] + bv) * scl);
                }
        }
    } else {
        unsigned short* vtp = qh + (size_t)2 * XEL;     // V transposed [bh][64][s]
        for (int jt = 0; jt < 3; ++jt) {
            int j = j0 + wn * 48 + jt * 16 + fr;
            float bv = bias[j];
            int h = j >> 6, dq = j & 63;
            for (int it = 0; it < 4; ++it) {
                int ibase = i0 + wm * 64 + it * 16 + g * 4;
                int bb = ibase >> 11, s = ibase & 2047;
                short4v o;
                for (int r = 0; r < 4; ++r) o[r] = (short)f2bf(acc[it][jt][r] + bv);
                *(short4v*)&vtp[((size_t)(bb * NH + h) * HD + dq) * S_LEN + s] = o;
            }
        }
    }
}

// ---------------- out projection: BM=64, BN=64, 768 blocks, XCD-coherent map ----------------
__global__ __launch_bounds__(256) void gemm_o_kernel(
    const unsigned short* A, const unsigned short* W, const float* bias, float* f_out)
{
    int bx = blockIdx.x;
    int im = (bx & 7) + 8 * (bx / 96);    // 64 M tiles of 64; same-A blocks share XCD
    int jn = (bx >> 3) % 12;              // 12 N tiles of 64
    int i0 = im * 64, j0 = jn * 64;

    __shared__ unsigned short As[64 * 64];    // 8KB
    __shared__ unsigned short Ws[64 * 64];    // 8KB

    int t = threadIdx.x;
    int w = t >> 6, lane = t & 63, g = lane >> 4, fr = lane & 15;
    int wm = w >> 1, wn = w & 1;              // wave tile 32 x 32

    f32x4 acc[2][2];
    for (int i = 0; i < 2; ++i)
        for (int j = 0; j < 2; ++j)
            acc[i][j] = (f32x4){0.f, 0.f, 0.f, 0.f};

    int boff = t * 16;

    for (int k0 = 0; k0 < DM; k0 += 64) {
        __syncthreads();
        for (int r = 0; r < 2; ++r) {
            int b = r * 4096 + boff;
            int row = b >> 7, colb = b & 127;
            gl_lds16(&A[(size_t)(i0 + row) * DM + k0 + (colb >> 1)],
                     (unsigned short*)((char*)As + b));
            gl_lds16(&W[(size_t)(j0 + row) * DM + k0 + (colb >> 1)],
                     (unsigned short*)((char*)Ws + b));
        }
        __syncthreads();
        for (int kk = 0; kk < 2; ++kk) {
            short8 af[2], wf[2];
            for (int it = 0; it < 2; ++it)
                af[it] = *(const short8*)&As[(wm * 32 + it * 16 + fr) * 64 + kk * 32 + g * 8];
            for (int jt = 0; jt < 2; ++jt)
                wf[jt] = *(const short8*)&Ws[(wn * 32 + jt * 16 + fr) * 64 + kk * 32 + g * 8];
            for (int it = 0; it < 2; ++it)
                for (int jt = 0; jt < 2; ++jt)
                    acc[it][jt] = __builtin_amdgcn_mfma_f32_16x16x32_bf16(af[it], wf[jt], acc[it][jt], 0, 0, 0);
        }
    }

    for (int jt = 0; jt < 2; ++jt) {
        int j = j0 + wn * 32 + jt * 16 + fr;
        float bv = bias[j];
        for (int it = 0; it < 2; ++it)
            for (int r = 0; r < 4; ++r) {
                int i = i0 + wm * 32 + it * 16 + g * 4 + r;
                f_out[(size_t)i * DM + j] = acc[it][jt][r] + bv;
            }
    }
}

// ---------------- flash attention (R13): span-pairing + idle-slot NEG_INF fill ----------------
__global__ __launch_bounds__(256) void attn_kernel(
    const unsigned short* q, const unsigned short* k, const unsigned short* vt,
    float* scores, unsigned short* attn)
{
    __shared__ unsigned short KV[2][8192];   // [buf][0..4095]=K tile, [4096..]=V^T tile (swizzled)
    __shared__ float P[4][16][68];
    int t = threadIdx.x;
    int w = t >> 6, lane = t & 63, g = lane >> 4, fr = lane & 15;
    float (*Pw)[68] = P[w];

    int bid = blockIdx.x;
    int bh = (bid & 7) * 3 + (bid >> 3) % 3;   // bh tied to XCD (K/V L2 locality)
    int s = bid / 24;                          // 0..31 pair index
    int myspan = (w < 2) ? s : 63 - s;
    int qbase = myspan * 32 + (w & 1) * 16;
    int myNt = ((myspan * 32 + 31) >> 6) + 1;
    int ntmax = (((63 - s) * 32 + 31) >> 6) + 1;
    int b = bh / NH, h = bh % NH;

    const unsigned short* qp = q + (size_t)bh * S_LEN * HD;
    const unsigned short* kp = k + (size_t)bh * S_LEN * HD;
    const unsigned short* vp = vt + (size_t)bh * HD * S_LEN;
    float* sp = scores + (size_t)bh * S_LEN * S_LEN;

    int srow2 = t >> 3;                 // 0..31
    int scb = (t & 7) * 16;             // byte col in 128B row
    int swzu = (fr & 7) * 8;            // frag-read swizzle in ushort units

    short8 qf0 = *(const short8*)&qp[(size_t)(qbase + fr) * HD + g * 8];
    short8 qf1 = *(const short8*)&qp[(size_t)(qbase + fr) * HD + 32 + g * 8];

    f32x4 acc[4];
    for (int jt = 0; jt < 4; ++jt) acc[jt] = (f32x4){0.f, 0.f, 0.f, 0.f};
    float m_run = -1e30f, l_run = 0.f;

    // idle-slot fill state
    f32x4 nv = (f32x4){NEGINF, NEGINF, NEGINF, NEGINF};
    int fill0 = myNt * 64;              // first strictly-masked col for this wave's rows
    int fillRow = 0;                    // next row (0..15) to fill in an idle slot

    // prologue stage tile 0 into buf 0 (pre-swizzled global source, linear LDS dest)
    for (int rd = 0; rd < 2; ++rd) {
        int row = rd * 32 + srow2;
        int sc = (scb ^ ((row & 7) << 4)) >> 1;
        gl_lds16(&kp[(size_t)row * HD + sc], &KV[0][(size_t)t * 8 + rd * 2048]);
        gl_lds16(&vp[(size_t)row * S_LEN + sc], &KV[0][4096 + (size_t)t * 8 + rd * 2048]);
    }

    int buf = 0;
    for (int kt = 0; kt < ntmax; ++kt) {
        __syncthreads();   // staging of tile kt complete; prev compute's LDS reads done
        if (kt + 1 < ntmax) {
            int kb2 = (kt + 1) * 64;
            for (int rd = 0; rd < 2; ++rd) {
                int row = rd * 32 + srow2;
                int sc = (scb ^ ((row & 7) << 4)) >> 1;
                gl_lds16(&kp[(size_t)(kb2 + row) * HD + sc], &KV[buf ^ 1][(size_t)t * 8 + rd * 2048]);
                gl_lds16(&vp[(size_t)row * S_LEN + kb2 + sc], &KV[buf ^ 1][4096 + (size_t)t * 8 + rd * 2048]);
            }
        }
        if (kt < myNt) {
            const unsigned short* Kb = KV[buf];
            const unsigned short* Vb = KV[buf] + 4096;
            int kb = kt * 64;
            bool diag = (kt == myNt - 1);

            short8 kf[4][2];
            for (int ktt = 0; ktt < 4; ++ktt) {
                int base = (ktt * 16 + fr) * 64;
                kf[ktt][0] = *(const short8*)&Kb[base + ((g * 8) ^ swzu)];
                kf[ktt][1] = *(const short8*)&Kb[base + ((32 + g * 8) ^ swzu)];
            }
            __builtin_amdgcn_s_setprio(1);
            f32x4 s4v[4];
            for (int ktt = 0; ktt < 4; ++ktt) {
                f32x4 s4 = (f32x4){0.f, 0.f, 0.f, 0.f};
                s4 = __builtin_amdgcn_mfma_f32_16x16x32_bf16(qf0, kf[ktt][0], s4, 0, 0, 0);
                s4 = __builtin_amdgcn_mfma_f32_16x16x32_bf16(qf1, kf[ktt][1], s4, 0, 0, 0);
                s4v[ktt] = s4;
            }
            __builtin_amdgcn_s_setprio(0);
            if (diag) {
                for (int ktt = 0; ktt < 4; ++ktt) {
                    int kg = kb + ktt * 16 + fr;     // C col = k index
                    for (int r = 0; r < 4; ++r) {
                        int qg = qbase + g * 4 + r;  // C row = q index
                        float val = (kg <= qg) ? s4v[ktt][r] : NEGINF;
                        Pw[g * 4 + r][ktt * 16 + fr] = val;
                    }
                }
            } else {
                for (int ktt = 0; ktt < 4; ++ktt)
                    for (int r = 0; r < 4; ++r)
                        Pw[g * 4 + r][ktt * 16 + fr] = s4v[ktt][r];
            }
            // coalesced nontemporal scores write (16 rows x 64 cols fp32)
            for (int pass = 0; pass < 4; ++pass) {
                int rr = pass * 4 + g;
                int cc = fr * 4;
                f32x4 vv = *(const f32x4*)&Pw[rr][cc];
                __builtin_nontemporal_store(vv, (f32x4*)&sp[(size_t)(qbase + rr) * S_LEN + kb + cc]);
            }
            // online softmax in A-frag layout (lane owns q-row fr); vector LDS reads
            f32x4 pA = *(const f32x4*)&Pw[fr][g * 8];
            f32x4 pB = *(const f32x4*)&Pw[fr][g * 8 + 4];
            f32x4 pC = *(const f32x4*)&Pw[fr][32 + g * 8];
            f32x4 pD = *(const f32x4*)&Pw[fr][32 + g * 8 + 4];
            float pv[16];
            pv[0]=pA[0]; pv[1]=pA[1]; pv[2]=pA[2]; pv[3]=pA[3];
            pv[4]=pB[0]; pv[5]=pB[1]; pv[6]=pB[2]; pv[7]=pB[3];
            pv[8]=pC[0]; pv[9]=pC[1]; pv[10]=pC[2]; pv[11]=pC[3];
            pv[12]=pD[0]; pv[13]=pD[1]; pv[14]=pD[2]; pv[15]=pD[3];
            float tmax = pv[0];
            for (int e = 1; e < 16; ++e) tmax = fmaxf(tmax, pv[e]);
            tmax = fmaxf(tmax, __shfl_xor(tmax, 16, 64));
            tmax = fmaxf(tmax, __shfl_xor(tmax, 32, 64));
            float m_new = fmaxf(m_run, tmax);
            float corr = __expf(m_run - m_new);
            float lsum = 0.f;
            for (int e = 0; e < 16; ++e) { pv[e] = __expf(pv[e] - m_new); lsum += pv[e]; }
            lsum += __shfl_xor(lsum, 16, 64);
            lsum += __shfl_xor(lsum, 32, 64);
            l_run = l_run * corr + lsum;
            m_run = m_new;
            short8 pa0, pa1;
            for (int e = 0; e < 8; ++e) { pa0[e] = (short)f2bf(pv[e]); pa1[e] = (short)f2bf(pv[8 + e]); }
            float fc[4];
            for (int r = 0; r < 4; ++r) fc[r] = __shfl(corr, g * 4 + r, 64);
            for (int jt = 0; jt < 4; ++jt)
                for (int r = 0; r < 4; ++r) acc[jt][r] *= fc[r];
            short8 vf[4][2];
            for (int jt = 0; jt < 4; ++jt) {
                int base = (jt * 16 + fr) * 64;
                vf[jt][0] = *(const short8*)&Vb[base + ((g * 8) ^ swzu)];
                vf[jt][1] = *(const short8*)&Vb[base + ((32 + g * 8) ^ swzu)];
            }
            __builtin_amdgcn_s_setprio(1);
            for (int jt = 0; jt < 4; ++jt) {
                acc[jt] = __builtin_amdgcn_mfma_f32_16x16x32_bf16(pa0, vf[jt][0], acc[jt], 0, 0, 0);
                acc[jt] = __builtin_amdgcn_mfma_f32_16x16x32_bf16(pa1, vf[jt][1], acc[jt], 0, 0, 0);
            }
            __builtin_amdgcn_s_setprio(0);
        } else {
            // idle slot (light wave done computing): issue 2 rows of NEG_INF fill
            for (int rr = fillRow; rr < fillRow + 2 && rr < 16; ++rr) {
                float* rowp = &sp[(size_t)(qbase + rr) * S_LEN];
                for (int c = fill0 + lane * 4; c < S_LEN; c += 256)
                    __builtin_nontemporal_store(nv, (f32x4*)(rowp + c));
            }
            fillRow += 2;
        }
        buf ^= 1;
    }
    // epilogue: divide by l, write attn bf16 [4096][768]
    float linv[4];
    for (int r = 0; r < 4; ++r) linv[r] = 1.0f / __shfl(l_run, g * 4 + r, 64);
    for (int jt = 0; jt < 4; ++jt) {
        int col = h * HD + jt * 16 + fr;
        for (int r = 0; r < 4; ++r) {
            int i = b * S_LEN + qbase + g * 4 + r;
            attn[(size_t)i * DM + col] = f2bf(acc[jt][r] * linv[r]);
        }
    }
    // NEG_INF fill for rows not covered by idle slots
    for (int rr = (fillRow < 16 ? fillRow : 16); rr < 16; ++rr) {
        float* rowp = &sp[(size_t)(qbase + rr) * S_LEN];
        for (int c = fill0 + lane * 4; c < S_LEN; c += 256)
            __builtin_nontemporal_store(nv, (f32x4*)(rowp + c));
    }
}

extern "C" void kernel_launch(void* const* d_in, const int* in_sizes, int n_in,
                              void* d_out, int out_size, void* d_ws, size_t ws_size,
                              hipStream_t stream) {
    const float* Q  = (const float*)d_in[0];
    const float* K  = (const float*)d_in[1];
    const float* V  = (const float*)d_in[2];
    // d_in[3] = mask (causal tril) — recomputed analytically, not read
    const float* Wq = (const float*)d_in[4];
    const float* bq = (const float*)d_in[5];
    const float* Wk = (const float*)d_in[6];
    const float* bk = (const float*)d_in[7];
    const float* Wv = (const float*)d_in[8];
    const float* bv = (const float*)d_in[9];
    const float* Wo = (const float*)d_in[10];
    const float* bo = (const float*)d_in[11];

    float* out = (float*)d_out;
    float* scores = out + (size_t)MROWS * DM;

    unsigned short* ws   = (unsigned short*)d_ws;
    unsigned short* Wbf  = ws;                              // 4 * WEL  (Wq,Wk,Wv,Wo bf16)
    unsigned short* qh   = Wbf + (size_t)4 * WEL;           // XEL q + XEL k (head-split) + XEL vt
    unsigned short* attnb = qh + (size_t)3 * XEL;           // XEL attn bf16

    cvt_w_kernel<<<dim3(288, 4), 256, 0, stream>>>(Wq, Wk, Wv, Wo, Wbf);
    gemm_qkv_kernel<<<dim3(256, 3), 256, 0, stream>>>(Q, K, V, Wbf, bq, bk, bv, qh);
    attn_kernel<<<dim3(768), 256, 0, stream>>>(qh, qh + (size_t)XEL, qh + (size_t)2 * XEL,
                                               scores, attnb);
    gemm_o_kernel<<<dim3(768), 256, 0, stream>>>(attnb, Wbf + (size_t)3 * WEL, bo, out);
}